// Round 5
// baseline (101.790 us; speedup 1.0000x reference)
//
#include <hip/hip_runtime.h>

#define PRESCALE 2.8853900817779268f   // 2*log2(e): exp2(PRESCALE*x) = e^{2x}

typedef short s16;
typedef unsigned short u16;
typedef unsigned int u32;
typedef __attribute__((ext_vector_type(8))) short short8v;  // 8 bf16 (4 VGPRs)
typedef __attribute__((ext_vector_type(4))) float f4;

// Raw v_exp_f32 / v_rcp_f32 — OCML exp2f carries denorm fixups (~3x VALU).
#if defined(__has_builtin)
#if __has_builtin(__builtin_amdgcn_exp2f)
#define EXP2(x) __builtin_amdgcn_exp2f(x)
#endif
#endif
#ifndef EXP2
#define EXP2(x) exp2f(x)
#endif
#define RCP(x) __builtin_amdgcn_rcpf(x)

__device__ inline u16 f2bf(float f){
  union{u32 i; float f;} v; v.f = f;
  u32 r = v.i + 0x7fffu + ((v.i >> 16) & 1u);
  return (u16)(r >> 16);
}

// ---------------- prep: W's -> bf16 (PRESCALE folded into W_ai, W_aw),
// img_feat -> bf16 padded to 256 rows, E gather -> bf16 + f32 copy to out.
__global__ __launch_bounds__(256) void k_prep(
    const float* __restrict__ W_img, const float* __restrict__ W_ai,
    const float* __restrict__ W_aw,  const float* __restrict__ img_feat,
    const int* __restrict__ question, const float* __restrict__ emb,
    s16* __restrict__ Wb, s16* __restrict__ Xb, s16* __restrict__ Eb,
    float* __restrict__ out){
  const int i = (blockIdx.x*256 + threadIdx.x)*4;
  if (blockIdx.y == 0){                       // 3 x 512 x 512 = 786432 elems
    const int w = i >> 18;
    const float sc = (w == 0) ? 1.f : PRESCALE;
    const float* src = (w==0) ? W_img : ((w==1) ? W_ai : W_aw);
    float4 v = *reinterpret_cast<const float4*>(src + (i & 262143));
    ushort4 o; o.x=f2bf(v.x*sc); o.y=f2bf(v.y*sc); o.z=f2bf(v.z*sc); o.w=f2bf(v.w*sc);
    *reinterpret_cast<ushort4*>(Wb + i) = o;
  } else if (blockIdx.y == 1){                // Xb 256x512 (zero-pad rows >=196)
    if (i >= 256*512) return;
    ushort4 o = make_ushort4(0,0,0,0);
    if ((i >> 9) < 196){
      float4 v = *reinterpret_cast<const float4*>(img_feat + i);
      o.x=f2bf(v.x); o.y=f2bf(v.y); o.z=f2bf(v.z); o.w=f2bf(v.w);
    }
    *reinterpret_cast<ushort4*>(Xb + i) = o;
  } else {                                    // Eb 1024x512 + out[:,512:]
    if (i >= 1024*512) return;
    const int t = i >> 9, c = i & 511;
    float4 v = *reinterpret_cast<const float4*>(emb + (size_t)question[t]*512 + c);
    *reinterpret_cast<float4*>(out + (size_t)t*1024 + 512 + c) = v;
    ushort4 o; o.x=f2bf(v.x); o.y=f2bf(v.y); o.z=f2bf(v.z); o.w=f2bf(v.w);
    *reinterpret_cast<ushort4*>(Eb + i) = o;
  }
}

// ---------------- MFMA GEMM: D[i][j] = sum_k A[i][k]*B[j][k] (K=512, bf16).
// Block 64x64 (4 waves, 2x2 of 32x32 wave-tiles); fragments straight from L2.
// Epilogue: + biasRow[i]*bs + biasCol[j]*bs, optional relu, f32 out (+ bf16 dup).
__global__ __launch_bounds__(256) void k_mfma(
    const s16* __restrict__ A, const s16* __restrict__ B,
    const float* __restrict__ biasRow, const float* __restrict__ biasCol,
    float bscale, int relu, float* __restrict__ O, int ldO,
    s16* __restrict__ Ob){
  const int tid = threadIdx.x, w = tid>>6, l = tid&63;
  const int m0 = blockIdx.x*64 + (w>>1)*32;
  const int n0 = blockIdx.y*64 + (w&1)*32;
  const int lr = l & 15, lg = l >> 4;
  f4 acc[2][2] = {};
  const s16* pa0 = A + (size_t)(m0 + lr)*512 + lg*8;
  const s16* pa1 = pa0 + 16*512;
  const s16* pb0 = B + (size_t)(n0 + lr)*512 + lg*8;
  const s16* pb1 = pb0 + 16*512;
  #pragma unroll 4
  for (int k = 0; k < 512; k += 32){
    short8v a0 = *reinterpret_cast<const short8v*>(pa0 + k);
    short8v a1 = *reinterpret_cast<const short8v*>(pa1 + k);
    short8v b0 = *reinterpret_cast<const short8v*>(pb0 + k);
    short8v b1 = *reinterpret_cast<const short8v*>(pb1 + k);
    acc[0][0] = __builtin_amdgcn_mfma_f32_16x16x32_bf16(a0, b0, acc[0][0], 0, 0, 0);
    acc[0][1] = __builtin_amdgcn_mfma_f32_16x16x32_bf16(a0, b1, acc[0][1], 0, 0, 0);
    acc[1][0] = __builtin_amdgcn_mfma_f32_16x16x32_bf16(a1, b0, acc[1][0], 0, 0, 0);
    acc[1][1] = __builtin_amdgcn_mfma_f32_16x16x32_bf16(a1, b1, acc[1][1], 0, 0, 0);
  }
  // D frag: col(=j/B-row dim) = lane&15, row(=i/A-row dim) = (lane>>4)*4 + reg
  #pragma unroll
  for (int i = 0; i < 2; ++i){
    #pragma unroll
    for (int j = 0; j < 2; ++j){
      const int nn = n0 + j*16 + lr;
      const float bc = biasCol ? biasCol[nn]*bscale : 0.f;
      #pragma unroll
      for (int p = 0; p < 4; ++p){
        const int mm = m0 + i*16 + lg*4 + p;
        float v = acc[i][j][p] + bc + (biasRow ? biasRow[mm]*bscale : 0.f);
        if (relu) v = fmaxf(v, 0.f);
        O[(size_t)mm*ldO + nn] = v;
        if (Ob) Ob[(size_t)mm*512 + nn] = (s16)f2bf(v);
      }
    }
  }
}

// ---------------- ST[r][t] = sum_h w[h] * rcp(exp2(AI'[r][h] + AWT'[h][t]) + 1)
// softmax(score) == softmax(-2*ST). grid(25,16), 512 thr: wave<->r, lane<->t.
__global__ __launch_bounds__(512) void k_score(
    const float* __restrict__ AI, const float* __restrict__ AWT,
    const float* __restrict__ w_att, float* __restrict__ ST){
  const int w = threadIdx.x >> 6, lane = threadIdx.x & 63;
  const int r = blockIdx.x*8 + w;
  if (r >= 196) return;
  const int t = blockIdx.y*64 + lane;
  const float* __restrict__ ai = AI + (size_t)r*512;
  const float* __restrict__ ap = AWT + t;
  float s = 0.f;
  #pragma unroll 2
  for (int h = 0; h < 512; h += 4){
    f4 a  = *reinterpret_cast<const f4*>(ai + h);
    f4 wv = *reinterpret_cast<const f4*>(w_att + h);
    float x0 = ap[(size_t)(h+0)*1024];
    float x1 = ap[(size_t)(h+1)*1024];
    float x2 = ap[(size_t)(h+2)*1024];
    float x3 = ap[(size_t)(h+3)*1024];
    s += wv.x * RCP(EXP2(a.x + x0) + 1.f);
    s += wv.y * RCP(EXP2(a.y + x1) + 1.f);
    s += wv.z * RCP(EXP2(a.z + x2) + 1.f);
    s += wv.w * RCP(EXP2(a.w + x3) + 1.f);
  }
  ST[(size_t)r*1024 + t] = s;
}

// ---------------- softmax(-2*ST) (folding /196) then ctx = w @ img.
// grid(64,8): 16 tokens x 64 e per block, 256 thr.
__global__ __launch_bounds__(256) void k_ctx(
    const float* __restrict__ ST, const float* __restrict__ img,
    float* __restrict__ out){
  __shared__ float wgt[196][16];
  __shared__ float red[16][16];
  const int tid = threadIdx.x;
  const int t0 = blockIdx.x*16, e0 = blockIdx.y*64;
  const int rs = tid>>4, tl = tid&15;

  float m = 1e30f;
  for (int k = 0; k < 13; ++k){
    const int r = rs + 16*k;
    if (r < 196) m = fminf(m, ST[(size_t)r*1024 + t0 + tl]);
  }
  red[rs][tl] = m;
  __syncthreads();
  if (tid < 16){
    float mm = red[0][tid];
    #pragma unroll
    for (int i = 1; i < 16; ++i) mm = fminf(mm, red[i][tid]);
    red[0][tid] = mm;
  }
  __syncthreads();
  const float mt = red[0][tl];
  float sum = 0.f;
  for (int k = 0; k < 13; ++k){
    const int r = rs + 16*k;
    if (r < 196){
      float p = EXP2(PRESCALE*(mt - ST[(size_t)r*1024 + t0 + tl]));
      wgt[r][tl] = p;
      sum += p;
    }
  }
  __syncthreads();
  red[rs][tl] = sum;
  __syncthreads();
  if (tid < 16){
    float ss = 0.f;
    #pragma unroll
    for (int i = 0; i < 16; ++i) ss += red[i][tid];
    red[0][tid] = 1.f / (ss * 196.f);
  }
  __syncthreads();
  const float inv = red[0][tl];
  for (int k = 0; k < 13; ++k){
    const int r = rs + 16*k;
    if (r < 196) wgt[r][tl] *= inv;
  }
  __syncthreads();

  const int e = e0 + (tid & 63), tq = tid >> 6;
  float acc[4] = {0.f, 0.f, 0.f, 0.f};
  const float* ip = img + e;
  #pragma unroll 4
  for (int r = 0; r < 196; ++r){
    const float f = ip[(size_t)r*512];
    float4 w4 = *reinterpret_cast<const float4*>(&wgt[r][tq*4]);
    acc[0] += w4.x*f; acc[1] += w4.y*f; acc[2] += w4.z*f; acc[3] += w4.w*f;
  }
  #pragma unroll
  for (int j = 0; j < 4; ++j)
    out[(size_t)(t0 + tq*4 + j)*1024 + e] = acc[j];
}

extern "C" void kernel_launch(void* const* d_in, const int* in_sizes, int n_in,
                              void* d_out, int out_size, void* d_ws, size_t ws_size,
                              hipStream_t stream) {
  const int*   question = (const int*)d_in[0];
  const float* img_feat = (const float*)d_in[1];
  const float* emb      = (const float*)d_in[2];
  const float* W_img    = (const float*)d_in[3];
  const float* b_img    = (const float*)d_in[4];
  const float* W_ai     = (const float*)d_in[5];
  const float* W_aw     = (const float*)d_in[6];
  const float* b_aw     = (const float*)d_in[7];
  const float* w_att    = (const float*)d_in[8];
  // d_in[9] = b_att: constant pre-softmax shift -> cancels in softmax.
  float* out = (float*)d_out;

  char* ws = (char*)d_ws;
  s16*   Wb    = (s16*)(ws);                  // 3x512x512 bf16 = 1572864 B
  s16*   Xb    = (s16*)(ws + 1572864);        // 256x512 bf16   = 262144 B
  s16*   Eb    = (s16*)(ws + 1835008);        // 1024x512 bf16  = 1048576 B
  float* img   = (float*)(ws + 2883584);      // 256x512 f32    = 524288 B
  s16*   img_b = (s16*)(ws + 3407872);        // 256x512 bf16   = 262144 B
  float* AI    = (float*)(ws + 3670016);      // 256x512 f32    = 524288 B
  float* AWT   = (float*)(ws + 4194304);      // 512x1024 f32   = 2097152 B
  float* ST    = (float*)(ws + 6291456);      // 196x1024 f32   = 802816 B

  hipLaunchKernelGGL(k_prep, dim3(768,3), dim3(256), 0, stream,
                     W_img, W_ai, W_aw, img_feat, question, emb, Wb, Xb, Eb, out);
  // img = relu(Xb @ W_imgT + b_img)  -> f32 img + bf16 img_b
  hipLaunchKernelGGL(k_mfma, dim3(4,8), dim3(256), 0, stream,
                     Xb, Wb, (const float*)nullptr, b_img, 1.0f, 1, img, 512, img_b);
  // AI = PRESCALE * (img @ W_aiT)    (scale folded into Wb[1])
  hipLaunchKernelGGL(k_mfma, dim3(4,8), dim3(256), 0, stream,
                     img_b, Wb + 262144, (const float*)nullptr, (const float*)nullptr,
                     0.0f, 0, AI, 512, (s16*)nullptr);
  // AWT[h][t] = PRESCALE * (E @ W_awT + b_aw)[t][h]  (A=W_aw, B=E -> D[h][t])
  hipLaunchKernelGGL(k_mfma, dim3(8,16), dim3(256), 0, stream,
                     Wb + 524288, Eb, b_aw, (const float*)nullptr,
                     PRESCALE, 0, AWT, 1024, (s16*)nullptr);
  hipLaunchKernelGGL(k_score, dim3(25,16), dim3(512), 0, stream, AI, AWT, w_att, ST);
  hipLaunchKernelGGL(k_ctx,   dim3(64,8),  dim3(256), 0, stream, ST, img, out);
}

// Round 6
// 82.696 us; speedup vs baseline: 1.2309x; 1.2309x over previous
//
#include <hip/hip_runtime.h>

#define PRESCALE 2.8853900817779268f   // 2*log2(e): exp2(PRESCALE*x) = e^{2x}

typedef short s16;
typedef unsigned short u16;
typedef unsigned int u32;
typedef __attribute__((ext_vector_type(8))) short short8v;  // 8 bf16 (4 VGPRs)
typedef __attribute__((ext_vector_type(4))) float f4;

// Raw v_exp_f32 / v_rcp_f32 — OCML exp2f carries denorm fixups (~3x VALU).
#if defined(__has_builtin)
#if __has_builtin(__builtin_amdgcn_exp2f)
#define EXP2(x) __builtin_amdgcn_exp2f(x)
#endif
#endif
#ifndef EXP2
#define EXP2(x) exp2f(x)
#endif
#define RCP(x) __builtin_amdgcn_rcpf(x)

__device__ inline u16 f2bf(float f){
  union{u32 i; float f;} v; v.f = f;
  u32 r = v.i + 0x7fffu + ((v.i >> 16) & 1u);
  return (u16)(r >> 16);
}

// ---------------- prep (1D grid, 1408 blocks x 256):
//  g <  196608: W's -> bf16 (PRESCALE folded into W_ai, W_aw)
//  g <  229376: img_feat -> bf16, zero-pad rows 196..255
//  else       : E = emb[question] -> bf16  +  f32 copy into out[:,512:]
__global__ __launch_bounds__(256) void k_prep(
    const float* __restrict__ W_img, const float* __restrict__ W_ai,
    const float* __restrict__ W_aw,  const float* __restrict__ img_feat,
    const int* __restrict__ question, const float* __restrict__ emb,
    s16* __restrict__ Wb, s16* __restrict__ Xb, s16* __restrict__ Eb,
    float* __restrict__ out){
  const int g = blockIdx.x*256 + threadIdx.x;
  if (g < 196608){
    const int i = g*4, w = i >> 18;
    const float sc = (w == 0) ? 1.f : PRESCALE;
    const float* src = (w==0) ? W_img : ((w==1) ? W_ai : W_aw);
    float4 v = *reinterpret_cast<const float4*>(src + (i & 262143));
    ushort4 o; o.x=f2bf(v.x*sc); o.y=f2bf(v.y*sc); o.z=f2bf(v.z*sc); o.w=f2bf(v.w*sc);
    *reinterpret_cast<ushort4*>(Wb + i) = o;
  } else if (g < 229376){
    const int i = (g - 196608)*4;
    ushort4 o = make_ushort4(0,0,0,0);
    if ((i >> 9) < 196){
      float4 v = *reinterpret_cast<const float4*>(img_feat + i);
      o.x=f2bf(v.x); o.y=f2bf(v.y); o.z=f2bf(v.z); o.w=f2bf(v.w);
    }
    *reinterpret_cast<ushort4*>(Xb + i) = o;
  } else {
    const int i = (g - 229376)*4;
    const int t = i >> 9, c = i & 511;
    float4 v = *reinterpret_cast<const float4*>(emb + (size_t)question[t]*512 + c);
    *reinterpret_cast<float4*>(out + (size_t)t*1024 + 512 + c) = v;
    ushort4 o; o.x=f2bf(v.x); o.y=f2bf(v.y); o.z=f2bf(v.z); o.w=f2bf(v.w);
    *reinterpret_cast<ushort4*>(Eb + i) = o;
  }
}

// 64x64 MFMA tile core: D[i][j] = sum_k A[i][k]*B[j][k], K=512 bf16.
// 4 waves, 2x2 of 32x32 wave-tiles; fragments straight from L2.
__device__ inline void mfma_core(const s16* __restrict__ A, const s16* __restrict__ B,
                                 int m0, int n0, int lr, int lg, f4 acc[2][2]){
  const s16* pa0 = A + (size_t)(m0 + lr)*512 + lg*8;
  const s16* pa1 = pa0 + 16*512;
  const s16* pb0 = B + (size_t)(n0 + lr)*512 + lg*8;
  const s16* pb1 = pb0 + 16*512;
  #pragma unroll 4
  for (int k = 0; k < 512; k += 32){
    short8v a0 = *reinterpret_cast<const short8v*>(pa0 + k);
    short8v a1 = *reinterpret_cast<const short8v*>(pa1 + k);
    short8v b0 = *reinterpret_cast<const short8v*>(pb0 + k);
    short8v b1 = *reinterpret_cast<const short8v*>(pb1 + k);
    acc[0][0] = __builtin_amdgcn_mfma_f32_16x16x32_bf16(a0, b0, acc[0][0], 0, 0, 0);
    acc[0][1] = __builtin_amdgcn_mfma_f32_16x16x32_bf16(a0, b1, acc[0][1], 0, 0, 0);
    acc[1][0] = __builtin_amdgcn_mfma_f32_16x16x32_bf16(a1, b0, acc[1][0], 0, 0, 0);
    acc[1][1] = __builtin_amdgcn_mfma_f32_16x16x32_bf16(a1, b1, acc[1][1], 0, 0, 0);
  }
}

// ---------------- fused independent GEMMs, 160 blocks:
//  blk < 32 : img = relu(Xb @ Wb_imgT + b_img) -> f32 img + bf16 img_b   (4x8 tiles)
//  blk >= 32: AWT4[h>>2][t][h&3] = (Wb_aw @ EbT)[h][t] + b_aw[h]*PRESCALE (8x16 tiles)
__global__ __launch_bounds__(256) void k_mfma_imgaw(
    const s16* __restrict__ Xb, const s16* __restrict__ Wb_img,
    const s16* __restrict__ Wb_aw, const s16* __restrict__ Eb,
    const float* __restrict__ b_img, const float* __restrict__ b_aw,
    float* __restrict__ img, s16* __restrict__ img_b,
    float* __restrict__ AWT4){
  const int tid = threadIdx.x, w = tid>>6, l = tid&63;
  const int lr = l & 15, lg = l >> 4;
  f4 acc[2][2] = {};
  if (blockIdx.x < 32){
    const int m0 = (blockIdx.x >> 3)*64 + (w>>1)*32;
    const int n0 = (blockIdx.x & 7)*64 + (w&1)*32;
    mfma_core(Xb, Wb_img, m0, n0, lr, lg, acc);
    #pragma unroll
    for (int i = 0; i < 2; ++i){
      #pragma unroll
      for (int j = 0; j < 2; ++j){
        const int nn = n0 + j*16 + lr;
        const float bc = b_img[nn];
        #pragma unroll
        for (int p = 0; p < 4; ++p){
          const int mm = m0 + i*16 + lg*4 + p;
          float v = fmaxf(acc[i][j][p] + bc, 0.f);
          img[(size_t)mm*512 + nn] = v;
          img_b[(size_t)mm*512 + nn] = (s16)f2bf(v);
        }
      }
    }
  } else {
    const int blk = blockIdx.x - 32;
    const int m0 = (blk >> 4)*64 + (w>>1)*32;     // h
    const int n0 = (blk & 15)*64 + (w&1)*32;      // t
    mfma_core(Wb_aw, Eb, m0, n0, lr, lg, acc);
    #pragma unroll
    for (int i = 0; i < 2; ++i){
      const int mb = m0 + i*16 + lg*4;            // mb%4==0; h = mb+p
      const float br = b_aw[mb] * PRESCALE;       // careful: bias is per-h (p-dependent)
      #pragma unroll
      for (int j = 0; j < 2; ++j){
        const int nn = n0 + j*16 + lr;
        f4 o;
        #pragma unroll
        for (int p = 0; p < 4; ++p)
          o[p] = acc[i][j][p] + b_aw[mb+p]*PRESCALE;
        *reinterpret_cast<f4*>(AWT4 + (size_t)(mb>>2)*4096 + nn*4) = o;
      }
      (void)br;
    }
  }
}

// ---------------- AI = img_b @ Wb_aiT (PRESCALE folded in Wb_ai). 32 blocks.
__global__ __launch_bounds__(256) void k_mfma_ai(
    const s16* __restrict__ img_b, const s16* __restrict__ Wb_ai,
    float* __restrict__ AI){
  const int tid = threadIdx.x, w = tid>>6, l = tid&63;
  const int lr = l & 15, lg = l >> 4;
  const int m0 = (blockIdx.x >> 3)*64 + (w>>1)*32;
  const int n0 = (blockIdx.x & 7)*64 + (w&1)*32;
  f4 acc[2][2] = {};
  mfma_core(img_b, Wb_ai, m0, n0, lr, lg, acc);
  #pragma unroll
  for (int i = 0; i < 2; ++i)
    #pragma unroll
    for (int j = 0; j < 2; ++j){
      const int nn = n0 + j*16 + lr;
      #pragma unroll
      for (int p = 0; p < 4; ++p){
        const int mm = m0 + i*16 + lg*4 + p;
        AI[(size_t)mm*512 + nn] = acc[i][j][p];
      }
    }
}

// ---------------- ST[r][t] = sum_h w[h]*rcp(exp2(AI'[r][h]+AW'[h][t])+1)
// softmax(score) == softmax(-2*ST). grid(25,16), 512 thr: wave<->r, lane<->t.
// AI rows + w_att in LDS (b128 broadcasts); AWT4 gives 1 dwordx4 per 4 h.
__global__ __launch_bounds__(512) void k_score(
    const float* __restrict__ AI, const float* __restrict__ AWT4,
    const float* __restrict__ w_att, float* __restrict__ ST){
  __shared__ float ais[8][512];
  __shared__ float ws[512];
  const int tid = threadIdx.x, w = tid>>6, lane = tid&63;
  const int r0 = blockIdx.x*8;
  for (int i = tid; i < 8*128; i += 512)
    reinterpret_cast<float4*>(&ais[0][0])[i] =
        reinterpret_cast<const float4*>(AI + (size_t)r0*512)[i];
  if (tid < 128)
    reinterpret_cast<float4*>(ws)[tid] = reinterpret_cast<const float4*>(w_att)[tid];
  __syncthreads();
  const int r = r0 + w;
  const int t = blockIdx.y*64 + lane;
  const float* __restrict__ ap = AWT4 + (size_t)t*4;
  float s0=0.f, s1=0.f, s2=0.f, s3=0.f;
  #pragma unroll 4
  for (int hg = 0; hg < 128; ++hg){
    f4 x  = *reinterpret_cast<const f4*>(ap + (size_t)hg*4096);
    f4 a  = *reinterpret_cast<const f4*>(&ais[w][hg*4]);
    f4 wv = *reinterpret_cast<const f4*>(&ws[hg*4]);
    s0 += wv.x * RCP(EXP2(a.x + x.x) + 1.f);
    s1 += wv.y * RCP(EXP2(a.y + x.y) + 1.f);
    s2 += wv.z * RCP(EXP2(a.z + x.z) + 1.f);
    s3 += wv.w * RCP(EXP2(a.w + x.w) + 1.f);
  }
  if (r < 196) ST[(size_t)r*1024 + t] = (s0+s1)+(s2+s3);
}

// ---------------- softmax(-2*ST) (folding /196) then ctx = w @ img.
// grid(64,8): 16 tokens x 64 e per block, 256 thr.
__global__ __launch_bounds__(256) void k_ctx(
    const float* __restrict__ ST, const float* __restrict__ img,
    float* __restrict__ out){
  __shared__ float wgt[196][16];
  __shared__ float red[16][16];
  const int tid = threadIdx.x;
  const int t0 = blockIdx.x*16, e0 = blockIdx.y*64;
  const int rs = tid>>4, tl = tid&15;

  float m = 1e30f;
  for (int k = 0; k < 13; ++k){
    const int r = rs + 16*k;
    if (r < 196) m = fminf(m, ST[(size_t)r*1024 + t0 + tl]);
  }
  red[rs][tl] = m;
  __syncthreads();
  if (tid < 16){
    float mm = red[0][tid];
    #pragma unroll
    for (int i = 1; i < 16; ++i) mm = fminf(mm, red[i][tid]);
    red[0][tid] = mm;
  }
  __syncthreads();
  const float mt = red[0][tl];
  float sum = 0.f;
  for (int k = 0; k < 13; ++k){
    const int r = rs + 16*k;
    if (r < 196){
      float p = EXP2(PRESCALE*(mt - ST[(size_t)r*1024 + t0 + tl]));
      wgt[r][tl] = p;
      sum += p;
    }
  }
  __syncthreads();
  red[rs][tl] = sum;
  __syncthreads();
  if (tid < 16){
    float ss = 0.f;
    #pragma unroll
    for (int i = 0; i < 16; ++i) ss += red[i][tid];
    red[0][tid] = 1.f / (ss * 196.f);
  }
  __syncthreads();
  const float inv = red[0][tl];
  for (int k = 0; k < 13; ++k){
    const int r = rs + 16*k;
    if (r < 196) wgt[r][tl] *= inv;
  }
  __syncthreads();

  const int e = e0 + (tid & 63), tq = tid >> 6;
  float acc[4] = {0.f, 0.f, 0.f, 0.f};
  const float* ip = img + e;
  #pragma unroll 4
  for (int r = 0; r < 196; ++r){
    const float f = ip[(size_t)r*512];
    float4 w4 = *reinterpret_cast<const float4*>(&wgt[r][tq*4]);
    acc[0] += w4.x*f; acc[1] += w4.y*f; acc[2] += w4.z*f; acc[3] += w4.w*f;
  }
  #pragma unroll
  for (int j = 0; j < 4; ++j)
    out[(size_t)(t0 + tq*4 + j)*1024 + e] = acc[j];
}

extern "C" void kernel_launch(void* const* d_in, const int* in_sizes, int n_in,
                              void* d_out, int out_size, void* d_ws, size_t ws_size,
                              hipStream_t stream) {
  const int*   question = (const int*)d_in[0];
  const float* img_feat = (const float*)d_in[1];
  const float* emb      = (const float*)d_in[2];
  const float* W_img    = (const float*)d_in[3];
  const float* b_img    = (const float*)d_in[4];
  const float* W_ai     = (const float*)d_in[5];
  const float* W_aw     = (const float*)d_in[6];
  const float* b_aw     = (const float*)d_in[7];
  const float* w_att    = (const float*)d_in[8];
  // d_in[9] = b_att: constant pre-softmax shift -> cancels in softmax.
  float* out = (float*)d_out;

  char* ws = (char*)d_ws;
  s16*   Wb    = (s16*)(ws);                  // 3x512x512 bf16 = 1572864 B
  s16*   Xb    = (s16*)(ws + 1572864);        // 256x512 bf16   = 262144 B
  s16*   Eb    = (s16*)(ws + 1835008);        // 1024x512 bf16  = 1048576 B
  float* img   = (float*)(ws + 2883584);      // 256x512 f32    = 524288 B
  s16*   img_b = (s16*)(ws + 3407872);        // 256x512 bf16   = 262144 B
  float* AI    = (float*)(ws + 3670016);      // 256x512 f32    = 524288 B
  float* AWT4  = (float*)(ws + 4194304);      // 128x1024x4 f32 = 2097152 B
  float* ST    = (float*)(ws + 6291456);      // 196x1024 f32   = 802816 B

  hipLaunchKernelGGL(k_prep, dim3(1408), dim3(256), 0, stream,
                     W_img, W_ai, W_aw, img_feat, question, emb, Wb, Xb, Eb, out);
  hipLaunchKernelGGL(k_mfma_imgaw, dim3(160), dim3(256), 0, stream,
                     Xb, Wb, Wb + 2*262144, Eb, b_img, b_aw, img, img_b, AWT4);
  hipLaunchKernelGGL(k_mfma_ai, dim3(32), dim3(256), 0, stream,
                     img_b, Wb + 262144, AI);
  hipLaunchKernelGGL(k_score, dim3(25,16), dim3(512), 0, stream, AI, AWT4, w_att, ST);
  hipLaunchKernelGGL(k_ctx,   dim3(64,8),  dim3(256), 0, stream, ST, img, out);
}